// Round 4
// baseline (439.665 us; speedup 1.0000x reference)
//
#include <hip/hip_runtime.h>
#include <hip/hip_bf16.h>

// PinSageConv on MI355X — round 4.
// qgemm v4: Qw lives in LDS (128 KB, XOR-swizzled) once per persistent block;
// h streamed global->VGPR fragments with register double-buffer; ZERO barriers
// in the K-loop. Transposed MFMA (D[n][v]) so each lane's acc quad = 4
// consecutive q bytes -> packed fp8 dword stores. Atomic tile queue.
// Workspace: q_fp8[100000][256] @0 (25.6MB) | aggF[20000][256] f32 @25.6MB
//            | WwB[256][512] bf16 @46,211,072 | tile counter @46,473,216.

#define M_TOTAL 100000
#define N_NODES 20000
#define T_NB    50
#define IN_F    256
#define HID_F   256
#define OUT_F   256
#define KCAT    512
#define QTILES  3125     // 100000 / 32

typedef __bf16 bf16x8 __attribute__((ext_vector_type(8)));
typedef float  floatx4 __attribute__((ext_vector_type(4)));
typedef float  v2f     __attribute__((ext_vector_type(2)));

__device__ __forceinline__ unsigned short f2bf(float f) {
    unsigned int u = __float_as_uint(f);
    u += 0x7fffu + ((u >> 16) & 1u);          // RTNE
    return (unsigned short)(u >> 16);
}
__device__ __forceinline__ void gload16(const void* g, void* l) {
    __builtin_amdgcn_global_load_lds(
        (const __attribute__((address_space(1))) unsigned int*)g,
        (__attribute__((address_space(3))) unsigned int*)l, 16, 0, 0);
}
__device__ __forceinline__ bf16x8 cvt_frag(float4 a, float4 b) {
    bf16x8 r;
    r[0] = (__bf16)a.x; r[1] = (__bf16)a.y; r[2] = (__bf16)a.z; r[3] = (__bf16)a.w;
    r[4] = (__bf16)b.x; r[5] = (__bf16)b.y; r[6] = (__bf16)b.z; r[7] = (__bf16)b.w;
    return r;
}

// ---------------------------------------------------------------------------
// Kernel 0: Ww f32 -> bf16 (131072 elems); also zero the qgemm tile counter.
// ---------------------------------------------------------------------------
__global__ __launch_bounds__(256)
void wcvt(const float* __restrict__ Ww, unsigned short* __restrict__ WwB,
          int* __restrict__ counter) {
    if (blockIdx.x == 0 && threadIdx.x == 0) *counter = 0;
    const int e = (blockIdx.x * 256 + threadIdx.x) * 4;
    const float4 v = *(const float4*)(Ww + e);
    ushort4 s;
    s.x = f2bf(v.x); s.y = f2bf(v.y); s.z = f2bf(v.z); s.w = f2bf(v.w);
    *(ushort4*)(WwB + e) = s;
}

// ---------------------------------------------------------------------------
// Kernel 1: q = fp8(relu(h @ Qw.T + Qb)), computed transposed: D[n][v].
// 256 persistent blocks x 512 threads (1/CU). Qw bf16 in LDS, swizzled
// chunk' = chunk ^ (n&7). Each wave grabs 32-node tiles from atomic queue;
// K-loop has no barriers: h fragments stream global->VGPR (dbuf), Qw frags
// from LDS, 16x16x32 bf16 MFMA, acc[nt=16][ct=2].
// ---------------------------------------------------------------------------
__global__ __launch_bounds__(512, 2)
void qgemm(const float* __restrict__ h, const float* __restrict__ Qw,
           const float* __restrict__ Qb, unsigned char* __restrict__ q,
           int* __restrict__ counter) {
    __shared__ unsigned short ldsW[256 * 256];   // [n][k] bf16, swizzled 16B chunks
    __shared__ float ldsQb[256];

    const int tid  = threadIdx.x;
    const int lane = tid & 63;
    const int quad = lane >> 4;
    const int fr   = lane & 15;

    // One-time: Qw fp32 -> bf16 swizzled into LDS. 8192 chunks / 512 thr = 16.
#pragma unroll
    for (int i = 0; i < 16; ++i) {
        const int C = tid + i * 512;
        const int n = C >> 5;
        const int c = C & 31;
        const float4 p0 = *(const float4*)(Qw + n * 256 + c * 8);
        const float4 p1 = *(const float4*)(Qw + n * 256 + c * 8 + 4);
        bf16x8 w = cvt_frag(p0, p1);
        *(bf16x8*)(ldsW + n * 256 + ((c ^ (n & 7)) * 8)) = w;
    }
    if (tid < 256) ldsQb[tid] = Qb[tid];
    __syncthreads();

    int tile = 0;
    if (lane == 0) tile = atomicAdd(counter, 1);
    tile = __shfl(tile, 0, 64);

    while (tile < QTILES) {
        int tile_next = 0;
        if (lane == 0) tile_next = atomicAdd(counter, 1);   // overlapped grab
        tile_next = __shfl(tile_next, 0, 64);

        const int v0 = tile * 32;
        const float* hp0 = h + (size_t)(v0 + fr) * IN_F + quad * 8;        // ct=0
        const float* hp1 = h + (size_t)(v0 + 16 + fr) * IN_F + quad * 8;   // ct=1

        float4 pf[2][4];
        pf[0][0] = *(const float4*)(hp0);
        pf[0][1] = *(const float4*)(hp0 + 4);
        pf[0][2] = *(const float4*)(hp1);
        pf[0][3] = *(const float4*)(hp1 + 4);

        floatx4 acc[16][2];
#pragma unroll
        for (int nt = 0; nt < 16; ++nt) {
            acc[nt][0] = (floatx4){0.f, 0.f, 0.f, 0.f};
            acc[nt][1] = (floatx4){0.f, 0.f, 0.f, 0.f};
        }

#pragma unroll
        for (int kb = 0; kb < 8; ++kb) {     // K=256, 32/step — NO barriers
            const int cur = kb & 1;
            if (kb < 7) {
                const int nxt = cur ^ 1;
                pf[nxt][0] = *(const float4*)(hp0 + (kb + 1) * 32);
                pf[nxt][1] = *(const float4*)(hp0 + (kb + 1) * 32 + 4);
                pf[nxt][2] = *(const float4*)(hp1 + (kb + 1) * 32);
                pf[nxt][3] = *(const float4*)(hp1 + (kb + 1) * 32 + 4);
            }
            const bf16x8 b0 = cvt_frag(pf[cur][0], pf[cur][1]);
            const bf16x8 b1 = cvt_frag(pf[cur][2], pf[cur][3]);
            const int cl = kb * 4 + quad;    // logical 16B chunk of this frag
#pragma unroll
            for (int nt = 0; nt < 16; ++nt) {
                const int n = nt * 16 + fr;
                const bf16x8 a = *(const bf16x8*)(ldsW + n * 256 + ((cl ^ (fr & 7)) * 8));
                acc[nt][0] = __builtin_amdgcn_mfma_f32_16x16x32_bf16(a, b0, acc[nt][0], 0, 0, 0);
                acc[nt][1] = __builtin_amdgcn_mfma_f32_16x16x32_bf16(a, b1, acc[nt][1], 0, 0, 0);
            }
        }

        // Epilogue: bias+relu, pack 4 consecutive n-bytes -> one dword store.
        // D: col(lane&15)=v within 16-group, row((lane>>4)*4+r)=n within nt*16.
#pragma unroll
        for (int nt = 0; nt < 16; ++nt) {
            const float4 bias = *(const float4*)(ldsQb + nt * 16 + quad * 4);
#pragma unroll
            for (int ct = 0; ct < 2; ++ct) {
                float x0 = acc[nt][ct][0] + bias.x;
                float x1 = acc[nt][ct][1] + bias.y;
                float x2 = acc[nt][ct][2] + bias.z;
                float x3 = acc[nt][ct][3] + bias.w;
                x0 = x0 > 0.f ? x0 : 0.f;  x1 = x1 > 0.f ? x1 : 0.f;
                x2 = x2 > 0.f ? x2 : 0.f;  x3 = x3 > 0.f ? x3 : 0.f;
                unsigned int d = __builtin_amdgcn_cvt_pk_fp8_f32(x0, x1, 0, false);
                d = __builtin_amdgcn_cvt_pk_fp8_f32(x2, x3, d, true);
                *(unsigned int*)(q + (size_t)(v0 + ct * 16 + fr) * HID_F + nt * 16 + quad * 4) = d;
            }
        }
        tile = tile_next;
    }
}

// ---------------------------------------------------------------------------
// Kernel 2: aggF[n] = sum_t w[n,t]*q[nb[n,t]] / sum_t w[n,t]  (fp32 out).
// One wave/node; 2 neighbors per load instruction (half-wave each, 8B/lane).
// ---------------------------------------------------------------------------
__global__ __launch_bounds__(256)
void aggk(const unsigned char* __restrict__ q, const int* __restrict__ nb,
          const float* __restrict__ w, float* __restrict__ aggF) {
    const int node = blockIdx.x * 4 + (threadIdx.x >> 6);
    const int lane = threadIdx.x & 63;

    int   idx_l = 0;
    float w_l   = 0.f;
    if (lane < T_NB) {
        idx_l = nb[(size_t)node * T_NB + lane];
        w_l   = w[(size_t)node * T_NB + lane];
    }
    float sw = w_l;
#pragma unroll
    for (int off = 32; off > 0; off >>= 1)
        sw += __shfl_xor(sw, off, 64);

    const int half = lane >> 5;
    const int foff = (lane & 31) * 8;
    float a[8];
#pragma unroll
    for (int j = 0; j < 8; ++j) a[j] = 0.f;

#pragma unroll
    for (int i = 0; i < T_NB / 2; ++i) {
        const int   t   = 2 * i + half;
        const int   idx = __shfl(idx_l, t, 64);
        const float wt  = __shfl(w_l, t, 64);
        const uint2 u   = *(const uint2*)(q + (size_t)idx * HID_F + foff);
        v2f p;
        p = __builtin_amdgcn_cvt_pk_f32_fp8(u.x, false); a[0] += wt * p[0]; a[1] += wt * p[1];
        p = __builtin_amdgcn_cvt_pk_f32_fp8(u.x, true);  a[2] += wt * p[0]; a[3] += wt * p[1];
        p = __builtin_amdgcn_cvt_pk_f32_fp8(u.y, false); a[4] += wt * p[0]; a[5] += wt * p[1];
        p = __builtin_amdgcn_cvt_pk_f32_fp8(u.y, true);  a[6] += wt * p[0]; a[7] += wt * p[1];
    }
#pragma unroll
    for (int j = 0; j < 8; ++j) a[j] += __shfl_xor(a[j], 32, 64);

    if (lane < 32) {
        const float inv = 1.0f / sw;
        float4 o0 = make_float4(a[0] * inv, a[1] * inv, a[2] * inv, a[3] * inv);
        float4 o1 = make_float4(a[4] * inv, a[5] * inv, a[6] * inv, a[7] * inv);
        *(float4*)(aggF + (size_t)node * HID_F + foff)     = o0;
        *(float4*)(aggF + (size_t)node * HID_F + foff + 4) = o1;
    }
}

// ---------------------------------------------------------------------------
// Kernel 3: out = relu(concat(h[nodeset], aggF) @ Ww.T + Wb).  M=20000 N=256 K=512.
// 64x128 tile, BK=64, async staging (A gathered fp32, B bf16). Wave = 64x32.
// ---------------------------------------------------------------------------
__global__ __launch_bounds__(256)
void fgemm(const float* __restrict__ h, const int* __restrict__ nodeset,
           const float* __restrict__ aggF, const unsigned short* __restrict__ WwB,
           const float* __restrict__ Wb, float* __restrict__ out) {
    __shared__ char smem[32768];
    float* ldsA = (float*)smem;                              // 64 rows x 16 chunks
    unsigned short* ldsB = (unsigned short*)(smem + 16384);  // 128 rows x 8 chunks

    const int tid  = threadIdx.x;
    const int row0 = blockIdx.x * 64;
    const int n0   = blockIdx.y * 128;
    const int lane = tid & 63;
    const int wv   = tid >> 6;
    const int wc   = wv << 5;
    const int fr   = lane & 15;
    const int fk   = (lane >> 4) << 3;
    const int ca   = fk >> 2;
    const int cbB  = fk >> 3;

    int nsrow[4];
#pragma unroll
    for (int i = 0; i < 4; ++i) {
        const int row = (tid + i * 256) >> 4;
        nsrow[i] = nodeset[min(row0 + row, N_NODES - 1)];
    }

    floatx4 acc[4][2];
#pragma unroll
    for (int i = 0; i < 4; ++i)
#pragma unroll
        for (int j = 0; j < 2; ++j)
            acc[i][j] = (floatx4){0.f, 0.f, 0.f, 0.f};

    for (int kb = 0; kb < 8; ++kb) {
        if (kb) __syncthreads();
#pragma unroll
        for (int i = 0; i < 4; ++i) {
            const int L   = tid + i * 256;
            const int row = L >> 4;
            const int cg  = (L & 15) ^ (row & 15);
            const float* src = (kb < 4)
                ? h    + (size_t)nsrow[i] * IN_F + kb * 64 + cg * 4
                : aggF + (size_t)min(row0 + row, N_NODES - 1) * HID_F + (kb - 4) * 64 + cg * 4;
            gload16(src, smem + L * 16);
        }
#pragma unroll
        for (int i = 0; i < 4; ++i) {
            const int L   = tid + i * 256;
            const int row = L >> 3;
            const int cg  = (L & 7) ^ (row & 7);
            gload16(WwB + (size_t)(n0 + row) * KCAT + kb * 64 + cg * 8, smem + 16384 + L * 16);
        }
        __syncthreads();

#pragma unroll
        for (int ks = 0; ks < 2; ++ks) {
            bf16x8 av[4], bv[2];
#pragma unroll
            for (int mt = 0; mt < 4; ++mt) {
                const int row = mt * 16 + fr;
                const int sw  = row & 15;
                const int c0  = ks * 8 + ca;
                const float4 p0 = *(const float4*)(ldsA + (row * 16 + (c0 ^ sw)) * 4);
                const float4 p1 = *(const float4*)(ldsA + (row * 16 + ((c0 + 1) ^ sw)) * 4);
                av[mt] = cvt_frag(p0, p1);
            }
#pragma unroll
            for (int nt = 0; nt < 2; ++nt) {
                const int row = wc + nt * 16 + fr;
                const int sw  = row & 7;
                bv[nt] = *reinterpret_cast<const bf16x8*>(ldsB + row * 64 + ((ks * 4 + cbB) ^ sw) * 8);
            }
#pragma unroll
            for (int mt = 0; mt < 4; ++mt)
#pragma unroll
                for (int nt = 0; nt < 2; ++nt)
                    acc[mt][nt] = __builtin_amdgcn_mfma_f32_16x16x32_bf16(av[mt], bv[nt], acc[mt][nt], 0, 0, 0);
        }
    }

    const int erow = (lane >> 4) << 2;
    const int ecol = lane & 15;
#pragma unroll
    for (int nt = 0; nt < 2; ++nt) {
        const int gcol = n0 + wc + nt * 16 + ecol;
        const float bias = Wb[gcol];
#pragma unroll
        for (int mt = 0; mt < 4; ++mt)
#pragma unroll
            for (int r = 0; r < 4; ++r) {
                const int gr = row0 + mt * 16 + erow + r;
                if (gr < N_NODES) {
                    const float v = acc[mt][nt][r] + bias;
                    out[(size_t)gr * OUT_F + gcol] = (v > 0.f ? v : 0.f);
                }
            }
    }
}

// ---------------------------------------------------------------------------
// Kernel 4: in-place row L2 normalize. One wave per row.
// ---------------------------------------------------------------------------
__global__ __launch_bounds__(256)
void normk(float* __restrict__ out) {
    const int row = blockIdx.x * 4 + (threadIdx.x >> 6);
    const int lane = threadIdx.x & 63;
    float4 v = *(float4*)(out + (size_t)row * OUT_F + lane * 4);
    float ss = v.x * v.x + v.y * v.y + v.z * v.z + v.w * v.w;
#pragma unroll
    for (int off = 32; off > 0; off >>= 1)
        ss += __shfl_xor(ss, off, 64);
    const float s = rsqrtf(ss);
    v.x *= s; v.y *= s; v.z *= s; v.w *= s;
    *(float4*)(out + (size_t)row * OUT_F + lane * 4) = v;
}

extern "C" void kernel_launch(void* const* d_in, const int* in_sizes, int n_in,
                              void* d_out, int out_size, void* d_ws, size_t ws_size,
                              hipStream_t stream) {
    const float* h        = (const float*)d_in[0];
    const int*   nodeset  = (const int*)d_in[1];
    const int*   nb_nodes = (const int*)d_in[2];
    const float* nb_w     = (const float*)d_in[3];
    const float* Qw       = (const float*)d_in[4];
    const float* Qb       = (const float*)d_in[5];
    const float* Ww       = (const float*)d_in[6];
    const float* Wb       = (const float*)d_in[7];
    float* out = (float*)d_out;

    unsigned char*  q    = (unsigned char*)d_ws;                          // 25.6 MB
    float*          aggF = (float*)((char*)d_ws + 25600000);              // 20.48 MB
    unsigned short* WwB  = (unsigned short*)((char*)d_ws + 46211072);     // 256 KB
    int*            ctr  = (int*)((char*)d_ws + 46473216);                // 4 B

    wcvt <<<dim3(128),                    256, 0, stream>>>(Ww, WwB, ctr);
    qgemm<<<dim3(256),                    512, 0, stream>>>(h, Qw, Qb, q, ctr);
    aggk <<<dim3(N_NODES / 4),            256, 0, stream>>>(q, nb_nodes, nb_w, aggF);
    fgemm<<<dim3((N_NODES + 63) / 64, 2), 256, 0, stream>>>(h, nodeset, aggF, WwB, Wb, out);
    normk<<<dim3(N_NODES / 4),            256, 0, stream>>>(out);
}

// Round 6
// 317.123 us; speedup vs baseline: 1.3864x; 1.3864x over previous
//
#include <hip/hip_runtime.h>
#include <hip/hip_bf16.h>

// PinSageConv on MI355X — round 6.
// qgemm v6: barrier-free streaming K-loop (Qw resident in LDS, h -> VGPR
// register dbuf). Epilogue staging redesigned to be race-free by construction:
// 16-node tiles, per-wave 4KB LDS staging buffer written ONCE per tile by all
// 64 lanes (unmasked), read ONCE, reused only across tiles (separated by the
// whole K-loop + explicit lgkmcnt fence). 448-thread blocks (7 waves) keep
// LDS at 157KB: 128K Qw + 1K Qb + 7x4K staging.
// v5's failure: two masked write/read phases reusing one 8-row buffer within
// a tile (WAR on identical LDS addresses) -> misplaced q entries.
// Workspace: q_fp8[100000][256] @0 (25.6MB) | aggF[20000][256] f32 @25.6MB
//            | WwB[256][512] bf16 @46,211,072 | tile counter @46,473,216.

#define M_TOTAL 100000
#define N_NODES 20000
#define T_NB    50
#define IN_F    256
#define HID_F   256
#define OUT_F   256
#define KCAT    512
#define QTILES  6250     // 100000 / 16

typedef __bf16 bf16x8 __attribute__((ext_vector_type(8)));
typedef float  floatx4 __attribute__((ext_vector_type(4)));
typedef float  v2f     __attribute__((ext_vector_type(2)));

__device__ __forceinline__ unsigned short f2bf(float f) {
    unsigned int u = __float_as_uint(f);
    u += 0x7fffu + ((u >> 16) & 1u);          // RTNE
    return (unsigned short)(u >> 16);
}
__device__ __forceinline__ void gload16(const void* g, void* l) {
    __builtin_amdgcn_global_load_lds(
        (const __attribute__((address_space(1))) unsigned int*)g,
        (__attribute__((address_space(3))) unsigned int*)l, 16, 0, 0);
}
__device__ __forceinline__ bf16x8 cvt_frag(float4 a, float4 b) {
    bf16x8 r;
    r[0] = (__bf16)a.x; r[1] = (__bf16)a.y; r[2] = (__bf16)a.z; r[3] = (__bf16)a.w;
    r[4] = (__bf16)b.x; r[5] = (__bf16)b.y; r[6] = (__bf16)b.z; r[7] = (__bf16)b.w;
    return r;
}

// ---------------------------------------------------------------------------
// Kernel 0: Ww f32 -> bf16 (131072 elems); also zero the qgemm tile counter.
// ---------------------------------------------------------------------------
__global__ __launch_bounds__(256)
void wcvt(const float* __restrict__ Ww, unsigned short* __restrict__ WwB,
          int* __restrict__ counter) {
    if (blockIdx.x == 0 && threadIdx.x == 0) *counter = 0;
    const int e = (blockIdx.x * 256 + threadIdx.x) * 4;
    const float4 v = *(const float4*)(Ww + e);
    ushort4 s;
    s.x = f2bf(v.x); s.y = f2bf(v.y); s.z = f2bf(v.z); s.w = f2bf(v.w);
    *(ushort4*)(WwB + e) = s;
}

// ---------------------------------------------------------------------------
// Kernel 1: q = fp8(relu(h @ Qw.T + Qb)), computed transposed: D[n][v].
// 256 blocks x 448 threads (7 waves, 1 block/CU). Qw bf16 in LDS (swizzled
// chunk' = chunk ^ (n&7)); waves pull 16-node tiles off an atomic queue;
// the K-loop has NO barriers (h streams global->VGPR with register dbuf).
// Epilogue: each lane packs 16 fp8 dwords (dword j=4*nt+quad of q row v0+fr);
// one unmasked write phase into the wave's 4KB staging buffer (rotation
// swizzle, 2-way banks = free), one read phase -> 4 contiguous 1KB stores.
// ---------------------------------------------------------------------------
__global__ __launch_bounds__(448)
void qgemm(const float* __restrict__ h, const float* __restrict__ Qw,
           const float* __restrict__ Qb, unsigned char* __restrict__ q,
           int* __restrict__ counter) {
    __shared__ unsigned short ldsW[256 * 256];   // 128 KB [n][k] bf16, swizzled chunks
    __shared__ float ldsQb[256];                 // 1 KB
    __shared__ unsigned int ldsS[7 * 1024];      // 28 KB: 7 waves x (16 rows x 64 dw)

    const int tid  = threadIdx.x;
    const int lane = tid & 63;
    const int wv   = tid >> 6;
    const int quad = lane >> 4;
    const int fr   = lane & 15;

    // One-time: Qw fp32 -> bf16 swizzled into LDS (8192 16B chunks).
    for (int C = tid; C < 8192; C += 448) {
        const int n = C >> 5;
        const int c = C & 31;
        const float4 p0 = *(const float4*)(Qw + n * 256 + c * 8);
        const float4 p1 = *(const float4*)(Qw + n * 256 + c * 8 + 4);
        bf16x8 w = cvt_frag(p0, p1);
        *(bf16x8*)(ldsW + n * 256 + ((c ^ (n & 7)) * 8)) = w;
    }
    if (tid < 256) ldsQb[tid] = Qb[tid];
    __syncthreads();

    unsigned int* const buf = ldsS + wv * 1024;

    int tile = 0;
    if (lane == 0) tile = atomicAdd(counter, 1);
    tile = __shfl(tile, 0, 64);

    while (tile < QTILES) {
        int tile_next = 0;
        if (lane == 0) tile_next = atomicAdd(counter, 1);   // overlapped grab
        tile_next = __shfl(tile_next, 0, 64);

        const int v0 = tile * 16;
        const float* hp = h + (size_t)(v0 + fr) * IN_F + quad * 8;

        float4 pf[2][2];
        pf[0][0] = *(const float4*)(hp);
        pf[0][1] = *(const float4*)(hp + 4);

        floatx4 acc[16];
#pragma unroll
        for (int nt = 0; nt < 16; ++nt)
            acc[nt] = (floatx4){0.f, 0.f, 0.f, 0.f};

#pragma unroll
        for (int kb = 0; kb < 8; ++kb) {     // K=256, 32/step — NO barriers
            const int cur = kb & 1;
            if (kb < 7) {
                const int nxt = cur ^ 1;
                pf[nxt][0] = *(const float4*)(hp + (kb + 1) * 32);
                pf[nxt][1] = *(const float4*)(hp + (kb + 1) * 32 + 4);
            }
            const bf16x8 b = cvt_frag(pf[cur][0], pf[cur][1]);
            const int cl = kb * 4 + quad;    // logical 16B chunk of this frag
#pragma unroll
            for (int nt = 0; nt < 16; ++nt) {
                const int n = nt * 16 + fr;
                const bf16x8 a = *(const bf16x8*)(ldsW + n * 256 + ((cl ^ (fr & 7)) * 8));
                acc[nt] = __builtin_amdgcn_mfma_f32_16x16x32_bf16(a, b, acc[nt], 0, 0, 0);
            }
        }

        // Pack: lane (quad, fr) holds dword j = 4*nt+quad of q row v0+fr.
        unsigned int d[16];
#pragma unroll
        for (int nt = 0; nt < 16; ++nt) {
            const float4 bias = *(const float4*)(ldsQb + nt * 16 + quad * 4);
            float x0 = acc[nt][0] + bias.x;
            float x1 = acc[nt][1] + bias.y;
            float x2 = acc[nt][2] + bias.z;
            float x3 = acc[nt][3] + bias.w;
            x0 = x0 > 0.f ? x0 : 0.f;  x1 = x1 > 0.f ? x1 : 0.f;
            x2 = x2 > 0.f ? x2 : 0.f;  x3 = x3 > 0.f ? x3 : 0.f;
            unsigned int dd = __builtin_amdgcn_cvt_pk_fp8_f32(x0, x1, 0, false);
            d[nt] = __builtin_amdgcn_cvt_pk_fp8_f32(x2, x3, dd, true);
        }

        // Fence: ensure last tile's staging reads fully drained (paranoia —
        // they're already separated by the whole K-loop) + compiler barrier.
        __asm volatile("s_waitcnt lgkmcnt(0)" ::: "memory");

        // Write phase: ALL 64 lanes, each buf dword written exactly once.
        // Row fr rotated by 4*fr dwords: pos p = (4c+quad+4*fr)&63.
#pragma unroll
        for (int c = 0; c < 16; ++c)
            buf[fr * 64 + ((4 * c + quad + 4 * fr) & 63)] = d[c];

        __asm volatile("s_waitcnt lgkmcnt(0)" ::: "memory");

        // Read phase: 4 contiguous 1KB stores (4 full q rows per instruction).
#pragma unroll
        for (int i = 0; i < 4; ++i) {
            const int rl = i * 4 + quad;     // row 0..15
            const int ch = fr;               // 16B chunk 0..15
            const uint4 val = *(const uint4*)(buf + rl * 64 + ((4 * ch + 4 * rl) & 63));
            *(uint4*)(q + (size_t)(v0 + rl) * HID_F + ch * 16) = val;
        }
        tile = tile_next;
    }
}

// ---------------------------------------------------------------------------
// Kernel 2: aggF[n] = sum_t w[n,t]*q[nb[n,t]] / sum_t w[n,t]  (fp32 out).
// One wave/node; 2 neighbors per load instruction (half-wave each, 8B/lane).
// ---------------------------------------------------------------------------
__global__ __launch_bounds__(256)
void aggk(const unsigned char* __restrict__ q, const int* __restrict__ nb,
          const float* __restrict__ w, float* __restrict__ aggF) {
    const int node = blockIdx.x * 4 + (threadIdx.x >> 6);
    const int lane = threadIdx.x & 63;

    int   idx_l = 0;
    float w_l   = 0.f;
    if (lane < T_NB) {
        idx_l = nb[(size_t)node * T_NB + lane];
        w_l   = w[(size_t)node * T_NB + lane];
    }
    float sw = w_l;
#pragma unroll
    for (int off = 32; off > 0; off >>= 1)
        sw += __shfl_xor(sw, off, 64);

    const int half = lane >> 5;
    const int foff = (lane & 31) * 8;
    float a[8];
#pragma unroll
    for (int j = 0; j < 8; ++j) a[j] = 0.f;

#pragma unroll
    for (int i = 0; i < T_NB / 2; ++i) {
        const int   t   = 2 * i + half;
        const int   idx = __shfl(idx_l, t, 64);
        const float wt  = __shfl(w_l, t, 64);
        const uint2 u   = *(const uint2*)(q + (size_t)idx * HID_F + foff);
        v2f p;
        p = __builtin_amdgcn_cvt_pk_f32_fp8(u.x, false); a[0] += wt * p[0]; a[1] += wt * p[1];
        p = __builtin_amdgcn_cvt_pk_f32_fp8(u.x, true);  a[2] += wt * p[0]; a[3] += wt * p[1];
        p = __builtin_amdgcn_cvt_pk_f32_fp8(u.y, false); a[4] += wt * p[0]; a[5] += wt * p[1];
        p = __builtin_amdgcn_cvt_pk_f32_fp8(u.y, true);  a[6] += wt * p[0]; a[7] += wt * p[1];
    }
#pragma unroll
    for (int j = 0; j < 8; ++j) a[j] += __shfl_xor(a[j], 32, 64);

    if (lane < 32) {
        const float inv = 1.0f / sw;
        float4 o0 = make_float4(a[0] * inv, a[1] * inv, a[2] * inv, a[3] * inv);
        float4 o1 = make_float4(a[4] * inv, a[5] * inv, a[6] * inv, a[7] * inv);
        *(float4*)(aggF + (size_t)node * HID_F + foff)     = o0;
        *(float4*)(aggF + (size_t)node * HID_F + foff + 4) = o1;
    }
}

// ---------------------------------------------------------------------------
// Kernel 3: out = relu(concat(h[nodeset], aggF) @ Ww.T + Wb).  M=20000 N=256 K=512.
// 64x128 tile, BK=64, async staging (A gathered fp32, B bf16). Wave = 64x32.
// ---------------------------------------------------------------------------
__global__ __launch_bounds__(256)
void fgemm(const float* __restrict__ h, const int* __restrict__ nodeset,
           const float* __restrict__ aggF, const unsigned short* __restrict__ WwB,
           const float* __restrict__ Wb, float* __restrict__ out) {
    __shared__ char smem[32768];
    float* ldsA = (float*)smem;                              // 64 rows x 16 chunks
    unsigned short* ldsB = (unsigned short*)(smem + 16384);  // 128 rows x 8 chunks

    const int tid  = threadIdx.x;
    const int row0 = blockIdx.x * 64;
    const int n0   = blockIdx.y * 128;
    const int lane = tid & 63;
    const int wv   = tid >> 6;
    const int wc   = wv << 5;
    const int fr   = lane & 15;
    const int fk   = (lane >> 4) << 3;
    const int ca   = fk >> 2;
    const int cbB  = fk >> 3;

    int nsrow[4];
#pragma unroll
    for (int i = 0; i < 4; ++i) {
        const int row = (tid + i * 256) >> 4;
        nsrow[i] = nodeset[min(row0 + row, N_NODES - 1)];
    }

    floatx4 acc[4][2];
#pragma unroll
    for (int i = 0; i < 4; ++i)
#pragma unroll
        for (int j = 0; j < 2; ++j)
            acc[i][j] = (floatx4){0.f, 0.f, 0.f, 0.f};

    for (int kb = 0; kb < 8; ++kb) {
        if (kb) __syncthreads();
#pragma unroll
        for (int i = 0; i < 4; ++i) {
            const int L   = tid + i * 256;
            const int row = L >> 4;
            const int cg  = (L & 15) ^ (row & 15);
            const float* src = (kb < 4)
                ? h    + (size_t)nsrow[i] * IN_F + kb * 64 + cg * 4
                : aggF + (size_t)min(row0 + row, N_NODES - 1) * HID_F + (kb - 4) * 64 + cg * 4;
            gload16(src, smem + L * 16);
        }
#pragma unroll
        for (int i = 0; i < 4; ++i) {
            const int L   = tid + i * 256;
            const int row = L >> 3;
            const int cg  = (L & 7) ^ (row & 7);
            gload16(WwB + (size_t)(n0 + row) * KCAT + kb * 64 + cg * 8, smem + 16384 + L * 16);
        }
        __syncthreads();

#pragma unroll
        for (int ks = 0; ks < 2; ++ks) {
            bf16x8 av[4], bv[2];
#pragma unroll
            for (int mt = 0; mt < 4; ++mt) {
                const int row = mt * 16 + fr;
                const int sw  = row & 15;
                const int c0  = ks * 8 + ca;
                const float4 p0 = *(const float4*)(ldsA + (row * 16 + (c0 ^ sw)) * 4);
                const float4 p1 = *(const float4*)(ldsA + (row * 16 + ((c0 + 1) ^ sw)) * 4);
                av[mt] = cvt_frag(p0, p1);
            }
#pragma unroll
            for (int nt = 0; nt < 2; ++nt) {
                const int row = wc + nt * 16 + fr;
                const int sw  = row & 7;
                bv[nt] = *reinterpret_cast<const bf16x8*>(ldsB + row * 64 + ((ks * 4 + cbB) ^ sw) * 8);
            }
#pragma unroll
            for (int mt = 0; mt < 4; ++mt)
#pragma unroll
                for (int nt = 0; nt < 2; ++nt)
                    acc[mt][nt] = __builtin_amdgcn_mfma_f32_16x16x32_bf16(av[mt], bv[nt], acc[mt][nt], 0, 0, 0);
        }
    }

    const int erow = (lane >> 4) << 2;
    const int ecol = lane & 15;
#pragma unroll
    for (int nt = 0; nt < 2; ++nt) {
        const int gcol = n0 + wc + nt * 16 + ecol;
        const float bias = Wb[gcol];
#pragma unroll
        for (int mt = 0; mt < 4; ++mt)
#pragma unroll
            for (int r = 0; r < 4; ++r) {
                const int gr = row0 + mt * 16 + erow + r;
                if (gr < N_NODES) {
                    const float v = acc[mt][nt][r] + bias;
                    out[(size_t)gr * OUT_F + gcol] = (v > 0.f ? v : 0.f);
                }
            }
    }
}

// ---------------------------------------------------------------------------
// Kernel 4: in-place row L2 normalize. One wave per row.
// ---------------------------------------------------------------------------
__global__ __launch_bounds__(256)
void normk(float* __restrict__ out) {
    const int row = blockIdx.x * 4 + (threadIdx.x >> 6);
    const int lane = threadIdx.x & 63;
    float4 v = *(float4*)(out + (size_t)row * OUT_F + lane * 4);
    float ss = v.x * v.x + v.y * v.y + v.z * v.z + v.w * v.w;
#pragma unroll
    for (int off = 32; off > 0; off >>= 1)
        ss += __shfl_xor(ss, off, 64);
    const float s = rsqrtf(ss);
    v.x *= s; v.y *= s; v.z *= s; v.w *= s;
    *(float4*)(out + (size_t)row * OUT_F + lane * 4) = v;
}

extern "C" void kernel_launch(void* const* d_in, const int* in_sizes, int n_in,
                              void* d_out, int out_size, void* d_ws, size_t ws_size,
                              hipStream_t stream) {
    const float* h        = (const float*)d_in[0];
    const int*   nodeset  = (const int*)d_in[1];
    const int*   nb_nodes = (const int*)d_in[2];
    const float* nb_w     = (const float*)d_in[3];
    const float* Qw       = (const float*)d_in[4];
    const float* Qb       = (const float*)d_in[5];
    const float* Ww       = (const float*)d_in[6];
    const float* Wb       = (const float*)d_in[7];
    float* out = (float*)d_out;

    unsigned char*  q    = (unsigned char*)d_ws;                          // 25.6 MB
    float*          aggF = (float*)((char*)d_ws + 25600000);              // 20.48 MB
    unsigned short* WwB  = (unsigned short*)((char*)d_ws + 46211072);     // 256 KB
    int*            ctr  = (int*)((char*)d_ws + 46473216);                // 4 B

    wcvt <<<dim3(128),                    256, 0, stream>>>(Ww, WwB, ctr);
    qgemm<<<dim3(256),                    448, 0, stream>>>(h, Qw, Qb, q, ctr);
    aggk <<<dim3(N_NODES / 4),            256, 0, stream>>>(q, nb_nodes, nb_w, aggF);
    fgemm<<<dim3((N_NODES + 63) / 64, 2), 256, 0, stream>>>(h, nodeset, aggF, WwB, Wb, out);
    normk<<<dim3(N_NODES / 4),            256, 0, stream>>>(out);
}

// Round 7
// 251.652 us; speedup vs baseline: 1.7471x; 1.2602x over previous
//
#include <hip/hip_runtime.h>
#include <hip/hip_bf16.h>

// PinSageConv on MI355X — round 7.
// qgemm v8: 64x256 block tile, A staged ONCE per block into 32KB LDS (bf16,
// XOR-swizzled) -> only 2 barriers/block; B-fragments stream directly from
// L1/L2-hot pre-converted QwB (coalesced 1KB loads, register dbuf); LDS
// 32KB/block -> ~5 blocks/CU (~20 waves) for latency hiding. fp8 epilogue via
// per-wave private LDS quadrant (reusing A region) -> sector-complete stores.
// v6 failed on occupancy: 128KB LDS-resident Qw = 1 block/CU = 1.75 waves/SIMD,
// everything idle (Occ 18.8%, MFMA 3.9%, HBM 0.6 TB/s).
// Workspace: q_fp8[100000][256] @0 (25.6MB) | aggF[20000][256] f32 @25.6MB
//            | QwB bf16 @46,080,000 | WwB bf16 @46,211,072.

#define M_TOTAL 100000
#define N_NODES 20000
#define T_NB    50
#define IN_F    256
#define HID_F   256
#define OUT_F   256
#define KCAT    512

typedef __bf16 bf16x8 __attribute__((ext_vector_type(8)));
typedef float  floatx4 __attribute__((ext_vector_type(4)));
typedef float  v2f     __attribute__((ext_vector_type(2)));

__device__ __forceinline__ unsigned short f2bf(float f) {
    unsigned int u = __float_as_uint(f);
    u += 0x7fffu + ((u >> 16) & 1u);          // RTNE
    return (unsigned short)(u >> 16);
}
__device__ __forceinline__ void gload16(const void* g, void* l) {
    __builtin_amdgcn_global_load_lds(
        (const __attribute__((address_space(1))) unsigned int*)g,
        (__attribute__((address_space(3))) unsigned int*)l, 16, 0, 0);
}
__device__ __forceinline__ bf16x8 cvt_frag(float4 a, float4 b) {
    bf16x8 r;
    r[0] = (__bf16)a.x; r[1] = (__bf16)a.y; r[2] = (__bf16)a.z; r[3] = (__bf16)a.w;
    r[4] = (__bf16)b.x; r[5] = (__bf16)b.y; r[6] = (__bf16)b.z; r[7] = (__bf16)b.w;
    return r;
}

// ---------------------------------------------------------------------------
// Kernel 0: convert Qw (65536 f32) and Ww (131072 f32) to bf16.
// ---------------------------------------------------------------------------
__global__ __launch_bounds__(256)
void wcvt(const float* __restrict__ Qw, const float* __restrict__ Ww,
          unsigned short* __restrict__ QwB, unsigned short* __restrict__ WwB) {
    const int e = (blockIdx.x * 256 + threadIdx.x) * 4;
    float4 v;
    unsigned short* dst;
    if (e < 65536) { v = *(const float4*)(Qw + e);           dst = QwB + e; }
    else           { v = *(const float4*)(Ww + (e - 65536)); dst = WwB + (e - 65536); }
    ushort4 s;
    s.x = f2bf(v.x); s.y = f2bf(v.y); s.z = f2bf(v.z); s.w = f2bf(v.w);
    *(ushort4*)dst = s;
}

// ---------------------------------------------------------------------------
// Kernel 1: q = fp8(relu(h @ Qw.T + Qb)).  M=100000 N=256(full) K=256.
// Block = 64 rows x 256 cols, 4 waves (wave = 64x64). A in LDS (bf16,
// swizzle chunk^=row&7), B-frags direct from global QwB (register dbuf).
// 2 barriers per block. Epilogue: fp8 into per-wave LDS quadrant -> uint4.
// ---------------------------------------------------------------------------
__global__ __launch_bounds__(256)
void qgemm(const float* __restrict__ h, const unsigned short* __restrict__ QwB,
           const float* __restrict__ Qb, unsigned char* __restrict__ q) {
    __shared__ unsigned short ldsA[64 * 256];   // 32 KB; reused as fp8 epi tile

    const int tid  = threadIdx.x;
    const int row0 = blockIdx.x * 64;
    const int lane = tid & 63;
    const int wv   = tid >> 6;
    const int wc   = wv << 6;              // wave's 64-col (n) slice
    const int quad = lane >> 4;
    const int fr   = lane & 15;

    // --- Stage A: 64 h-rows fp32 -> bf16 -> swizzled LDS (2048 8-elem chunks).
#pragma unroll
    for (int i = 0; i < 8; ++i) {
        const int C = tid + i * 256;
        const int r = C >> 5;
        const int c = C & 31;
        const int gr = min(row0 + r, M_TOTAL - 1);
        const float4 p0 = *(const float4*)(h + (size_t)gr * IN_F + c * 8);
        const float4 p1 = *(const float4*)(h + (size_t)gr * IN_F + c * 8 + 4);
        *(bf16x8*)(ldsA + r * 256 + ((c ^ (r & 7)) * 8)) = cvt_frag(p0, p1);
    }
    // bias for this lane's 4 n-columns (one per nt), loaded while staging lands
    float bias[4];
#pragma unroll
    for (int nt = 0; nt < 4; ++nt) bias[nt] = Qb[wc + nt * 16 + fr];
    __syncthreads();

    floatx4 acc[4][4];
#pragma unroll
    for (int i = 0; i < 4; ++i)
#pragma unroll
        for (int j = 0; j < 4; ++j)
            acc[i][j] = (floatx4){0.f, 0.f, 0.f, 0.f};

    // B-frag base: row n = wc + nt*16 + fr, k-chunk = kb*4 + quad.
    const unsigned short* bp = QwB + (size_t)(wc + fr) * IN_F + quad * 8;

    bf16x8 bvp[2][4];
#pragma unroll
    for (int nt = 0; nt < 4; ++nt)
        bvp[0][nt] = *(const bf16x8*)(bp + nt * 16 * IN_F);

#pragma unroll
    for (int kb = 0; kb < 8; ++kb) {       // K=256, 32/step — no barriers
        const int cur = kb & 1;
        if (kb < 7) {
#pragma unroll
            for (int nt = 0; nt < 4; ++nt)
                bvp[cur ^ 1][nt] = *(const bf16x8*)(bp + nt * 16 * IN_F + (kb + 1) * 32);
        }
        bf16x8 av[4];
#pragma unroll
        for (int mt = 0; mt < 4; ++mt) {
            const int r = mt * 16 + fr;
            const int c = kb * 4 + quad;
            av[mt] = *(const bf16x8*)(ldsA + r * 256 + ((c ^ (r & 7)) * 8));
        }
#pragma unroll
        for (int mt = 0; mt < 4; ++mt)
#pragma unroll
            for (int nt = 0; nt < 4; ++nt)
                acc[mt][nt] = __builtin_amdgcn_mfma_f32_16x16x32_bf16(av[mt], bvp[cur][nt], acc[mt][nt], 0, 0, 0);
    }

    // --- Epilogue: all waves done reading ldsA, then reuse it as fp8 tile.
    __syncthreads();
    unsigned char* const epi = (unsigned char*)ldsA + wv * 4096;   // 64r x 64c
#pragma unroll
    for (int mt = 0; mt < 4; ++mt)
#pragma unroll
        for (int nt = 0; nt < 4; ++nt)
#pragma unroll
            for (int r = 0; r < 4; ++r) {
                float v = acc[mt][nt][r] + bias[nt];
                v = v > 0.f ? v : 0.f;
                epi[(mt * 16 + quad * 4 + r) * 64 + nt * 16 + fr] =
                    (unsigned char)(__builtin_amdgcn_cvt_pk_fp8_f32(v, 0.f, 0, false) & 0xff);
            }
    __asm volatile("s_waitcnt lgkmcnt(0)" ::: "memory");   // in-wave write->read order

    // Sector-complete stores: 16 rows x 4 x 16B segments per instruction.
#pragma unroll
    for (int i = 0; i < 4; ++i) {
        const int r   = i * 16 + (lane >> 2);
        const int seg = lane & 3;
        const uint4 val = *(const uint4*)(epi + r * 64 + seg * 16);
        const int gr = row0 + r;
        if (gr < M_TOTAL)
            *(uint4*)(q + (size_t)gr * HID_F + wc + seg * 16) = val;
    }
}

// ---------------------------------------------------------------------------
// Kernel 2: aggF[n] = sum_t w[n,t]*q[nb[n,t]] / sum_t w[n,t]  (fp32 out).
// One wave/node; 2 neighbors per load instruction (half-wave each, 8B/lane).
// ---------------------------------------------------------------------------
__global__ __launch_bounds__(256)
void aggk(const unsigned char* __restrict__ q, const int* __restrict__ nb,
          const float* __restrict__ w, float* __restrict__ aggF) {
    const int node = blockIdx.x * 4 + (threadIdx.x >> 6);
    const int lane = threadIdx.x & 63;

    int   idx_l = 0;
    float w_l   = 0.f;
    if (lane < T_NB) {
        idx_l = nb[(size_t)node * T_NB + lane];
        w_l   = w[(size_t)node * T_NB + lane];
    }
    float sw = w_l;
#pragma unroll
    for (int off = 32; off > 0; off >>= 1)
        sw += __shfl_xor(sw, off, 64);

    const int half = lane >> 5;
    const int foff = (lane & 31) * 8;
    float a[8];
#pragma unroll
    for (int j = 0; j < 8; ++j) a[j] = 0.f;

#pragma unroll
    for (int i = 0; i < T_NB / 2; ++i) {
        const int   t   = 2 * i + half;
        const int   idx = __shfl(idx_l, t, 64);
        const float wt  = __shfl(w_l, t, 64);
        const uint2 u   = *(const uint2*)(q + (size_t)idx * HID_F + foff);
        v2f p;
        p = __builtin_amdgcn_cvt_pk_f32_fp8(u.x, false); a[0] += wt * p[0]; a[1] += wt * p[1];
        p = __builtin_amdgcn_cvt_pk_f32_fp8(u.x, true);  a[2] += wt * p[0]; a[3] += wt * p[1];
        p = __builtin_amdgcn_cvt_pk_f32_fp8(u.y, false); a[4] += wt * p[0]; a[5] += wt * p[1];
        p = __builtin_amdgcn_cvt_pk_f32_fp8(u.y, true);  a[6] += wt * p[0]; a[7] += wt * p[1];
    }
#pragma unroll
    for (int j = 0; j < 8; ++j) a[j] += __shfl_xor(a[j], 32, 64);

    if (lane < 32) {
        const float inv = 1.0f / sw;
        float4 o0 = make_float4(a[0] * inv, a[1] * inv, a[2] * inv, a[3] * inv);
        float4 o1 = make_float4(a[4] * inv, a[5] * inv, a[6] * inv, a[7] * inv);
        *(float4*)(aggF + (size_t)node * HID_F + foff)     = o0;
        *(float4*)(aggF + (size_t)node * HID_F + foff + 4) = o1;
    }
}

// ---------------------------------------------------------------------------
// Kernel 3: out = relu(concat(h[nodeset], aggF) @ Ww.T + Wb).  M=20000 N=256 K=512.
// 64x128 tile, BK=64, async staging (A gathered fp32, B bf16). Wave = 64x32.
// ---------------------------------------------------------------------------
__global__ __launch_bounds__(256)
void fgemm(const float* __restrict__ h, const int* __restrict__ nodeset,
           const float* __restrict__ aggF, const unsigned short* __restrict__ WwB,
           const float* __restrict__ Wb, float* __restrict__ out) {
    __shared__ char smem[32768];
    float* ldsA = (float*)smem;                              // 64 rows x 16 chunks
    unsigned short* ldsB = (unsigned short*)(smem + 16384);  // 128 rows x 8 chunks

    const int tid  = threadIdx.x;
    const int row0 = blockIdx.x * 64;
    const int n0   = blockIdx.y * 128;
    const int lane = tid & 63;
    const int wv   = tid >> 6;
    const int wc   = wv << 5;
    const int fr   = lane & 15;
    const int fk   = (lane >> 4) << 3;
    const int ca   = fk >> 2;
    const int cbB  = fk >> 3;

    int nsrow[4];
#pragma unroll
    for (int i = 0; i < 4; ++i) {
        const int row = (tid + i * 256) >> 4;
        nsrow[i] = nodeset[min(row0 + row, N_NODES - 1)];
    }

    floatx4 acc[4][2];
#pragma unroll
    for (int i = 0; i < 4; ++i)
#pragma unroll
        for (int j = 0; j < 2; ++j)
            acc[i][j] = (floatx4){0.f, 0.f, 0.f, 0.f};

    for (int kb = 0; kb < 8; ++kb) {
        if (kb) __syncthreads();
#pragma unroll
        for (int i = 0; i < 4; ++i) {
            const int L   = tid + i * 256;
            const int row = L >> 4;
            const int cg  = (L & 15) ^ (row & 15);
            const float* src = (kb < 4)
                ? h    + (size_t)nsrow[i] * IN_F + kb * 64 + cg * 4
                : aggF + (size_t)min(row0 + row, N_NODES - 1) * HID_F + (kb - 4) * 64 + cg * 4;
            gload16(src, smem + L * 16);
        }
#pragma unroll
        for (int i = 0; i < 4; ++i) {
            const int L   = tid + i * 256;
            const int row = L >> 3;
            const int cg  = (L & 7) ^ (row & 7);
            gload16(WwB + (size_t)(n0 + row) * KCAT + kb * 64 + cg * 8, smem + 16384 + L * 16);
        }
        __syncthreads();

#pragma unroll
        for (int ks = 0; ks < 2; ++ks) {
            bf16x8 av[4], bv[2];
#pragma unroll
            for (int mt = 0; mt < 4; ++mt) {
                const int row = mt * 16 + fr;
                const int sw  = row & 15;
                const int c0  = ks * 8 + ca;
                const float4 p0 = *(const float4*)(ldsA + (row * 16 + (c0 ^ sw)) * 4);
                const float4 p1 = *(const float4*)(ldsA + (row * 16 + ((c0 + 1) ^ sw)) * 4);
                av[mt] = cvt_frag(p0, p1);
            }
#pragma unroll
            for (int nt = 0; nt < 2; ++nt) {
                const int row = wc + nt * 16 + fr;
                const int sw  = row & 7;
                bv[nt] = *reinterpret_cast<const bf16x8*>(ldsB + row * 64 + ((ks * 4 + cbB) ^ sw) * 8);
            }
#pragma unroll
            for (int mt = 0; mt < 4; ++mt)
#pragma unroll
                for (int nt = 0; nt < 2; ++nt)
                    acc[mt][nt] = __builtin_amdgcn_mfma_f32_16x16x32_bf16(av[mt], bv[nt], acc[mt][nt], 0, 0, 0);
        }
    }

    const int erow = (lane >> 4) << 2;
    const int ecol = lane & 15;
#pragma unroll
    for (int nt = 0; nt < 2; ++nt) {
        const int gcol = n0 + wc + nt * 16 + ecol;
        const float bias = Wb[gcol];
#pragma unroll
        for (int mt = 0; mt < 4; ++mt)
#pragma unroll
            for (int r = 0; r < 4; ++r) {
                const int gr = row0 + mt * 16 + erow + r;
                if (gr < N_NODES) {
                    const float v = acc[mt][nt][r] + bias;
                    out[(size_t)gr * OUT_F + gcol] = (v > 0.f ? v : 0.f);
                }
            }
    }
}

// ---------------------------------------------------------------------------
// Kernel 4: in-place row L2 normalize. One wave per row.
// ---------------------------------------------------------------------------
__global__ __launch_bounds__(256)
void normk(float* __restrict__ out) {
    const int row = blockIdx.x * 4 + (threadIdx.x >> 6);
    const int lane = threadIdx.x & 63;
    float4 v = *(float4*)(out + (size_t)row * OUT_F + lane * 4);
    float ss = v.x * v.x + v.y * v.y + v.z * v.z + v.w * v.w;
#pragma unroll
    for (int off = 32; off > 0; off >>= 1)
        ss += __shfl_xor(ss, off, 64);
    const float s = rsqrtf(ss);
    v.x *= s; v.y *= s; v.z *= s; v.w *= s;
    *(float4*)(out + (size_t)row * OUT_F + lane * 4) = v;
}

extern "C" void kernel_launch(void* const* d_in, const int* in_sizes, int n_in,
                              void* d_out, int out_size, void* d_ws, size_t ws_size,
                              hipStream_t stream) {
    const float* h        = (const float*)d_in[0];
    const int*   nodeset  = (const int*)d_in[1];
    const int*   nb_nodes = (const int*)d_in[2];
    const float* nb_w     = (const float*)d_in[3];
    const float* Qw       = (const float*)d_in[4];
    const float* Qb       = (const float*)d_in[5];
    const float* Ww       = (const float*)d_in[6];
    const float* Wb       = (const float*)d_in[7];
    float* out = (float*)d_out;

    unsigned char*  q    = (unsigned char*)d_ws;                          // 25.6 MB
    float*          aggF = (float*)((char*)d_ws + 25600000);              // 20.48 MB
    unsigned short* QwB  = (unsigned short*)((char*)d_ws + 46080000);     // 128 KB
    unsigned short* WwB  = (unsigned short*)((char*)d_ws + 46211072);     // 256 KB

    wcvt <<<dim3(192),                    256, 0, stream>>>(Qw, Ww, QwB, WwB);
    qgemm<<<dim3((M_TOTAL + 63) / 64),    256, 0, stream>>>(h, QwB, Qb, q);
    aggk <<<dim3(N_NODES / 4),            256, 0, stream>>>(q, nb_nodes, nb_w, aggF);
    fgemm<<<dim3((N_NODES + 63) / 64, 2), 256, 0, stream>>>(h, nodeset, aggF, WwB, Wb, out);
    normk<<<dim3(N_NODES / 4),            256, 0, stream>>>(out);
}